// Round 11
// baseline (169.945 us; speedup 1.0000x reference)
//
#include <hip/hip_runtime.h>

typedef __bf16 bf16x8 __attribute__((ext_vector_type(8)));
typedef float f32x4 __attribute__((ext_vector_type(4)));
typedef unsigned short u16;
typedef unsigned long long u64;

#define HDIM 768
#define NHEADS 12
#define SEQ 1024
#define NBATCH 4
#define ROWS 4096      // B*T
#define QKV3 2304
#define INTERDIM 3072

__device__ __forceinline__ u16 f2bf(float f) {
  union { float f; unsigned int u; } v; v.f = f;
  unsigned int r = v.u + 0x7fffu + ((v.u >> 16) & 1u);
  return (u16)(r >> 16);
}

// async global->LDS, 16B per lane. LDS dest is wave-uniform base + lane*16.
__device__ __forceinline__ void gload16(const u16* g, u16* l) {
  __builtin_amdgcn_global_load_lds(
      (const __attribute__((address_space(1))) void*)g,
      (__attribute__((address_space(3))) void*)l, 16, 0, 0);
}

__device__ __forceinline__ unsigned ldsoff(const void* p) {
  return (unsigned)(unsigned long long)(const __attribute__((address_space(3))) char*)p;
}

// hardware transpose read: lane gets 4 bf16 at [a, a+32B, a+64B, a+96B]
__device__ __forceinline__ u64 tr8(unsigned a) {
  u64 r;
  asm volatile("ds_read_b64_tr_b16 %0, %1" : "=v"(r) : "v"(a));
  return r;
}

union B8 { u64 q[2]; bf16x8 v; };

// ---------------- fused pre-pass: x->bf16 + 4 weight transposes ----------------
__global__ __launch_bounds__(256) void k_prep(
    const float* __restrict__ x, u16* __restrict__ xb,
    const float* __restrict__ wqkv, u16* __restrict__ wqkvT,
    const float* __restrict__ wo, u16* __restrict__ woT,
    const float* __restrict__ w1, u16* __restrict__ w1T,
    const float* __restrict__ w2, u16* __restrict__ w2T) {
  __shared__ float tile[32][33];
  int bid = blockIdx.x, tid = threadIdx.x;
  if (bid < 3072) {
    int i = bid * 256 + tid;
    float4 f = reinterpret_cast<const float4*>(x)[i];
    ushort4 o;
    o.x = f2bf(f.x); o.y = f2bf(f.y); o.z = f2bf(f.z); o.w = f2bf(f.w);
    reinterpret_cast<ushort4*>(xb)[i] = o;
    return;
  }
  const float* in; u16* outp; int K, N, t;
  if (bid < 4800)      { in = wqkv; outp = wqkvT; K = 768;  N = 2304; t = bid - 3072; }
  else if (bid < 5376) { in = wo;   outp = woT;   K = 768;  N = 768;  t = bid - 4800; }
  else if (bid < 7680) { in = w1;   outp = w1T;   K = 768;  N = 3072; t = bid - 5376; }
  else                 { in = w2;   outp = w2T;   K = 3072; N = 768;  t = bid - 7680; }
  int ntx = N >> 5;
  int bx = t % ntx, by = t / ntx;
  int tx = tid & 31, ty = tid >> 5;
  int n0 = bx * 32, k0 = by * 32;
#pragma unroll
  for (int i = 0; i < 32; i += 8)
    tile[ty + i][tx] = in[(size_t)(k0 + ty + i) * N + n0 + tx];
  __syncthreads();
#pragma unroll
  for (int i = 0; i < 32; i += 8)
    outp[(size_t)(n0 + ty + i) * K + k0 + tx] = f2bf(tile[tx][ty + i]);
}

// ============ MFMA GEMM, BK=32, TRIPLE-buffer LDS, 1 barrier/tile ============
// C = A[M][K] * Bt[N][K]^T. Prologue stages tiles 0,1; tile t:
//   vmcnt(ISS)+s_barrier   (stage(t) landed for every wave; t+1 in flight)
//   issue STAGE(t+2) -> buf[(t+2)%3]   (disjoint from buf[t%3] being read)
//   ds_read frags (compiler lgkmcnt) ; MFMA
// Safety: a wave's tile t-1 reads of buf[(t-1)%3]==buf[(t+2)%3] are consumed
// by its own MFMAs before bar(t), so the overwrite can't race.
// Swizzle (both sides): 8-elem chunk ^= (row>>1)&3  (verified: 0 conflicts).
// BM=256,BN=128: waves 2x2, wave 128x64.  BM=128,BN=64: waves 4x1, wave 32x64.
// modes: 0: obf=bf16(C)                                   (qkv)
//        1: t=e1[idx]+0.2*C+e2[col]; of32=t, obf=bf16(t)  (w_o + residual)
//        2: obf=bf16(relu(C+e1[col]))                     (ffn1)
//        3: of32[z*M*N+idx]=C                             (ffn2 split-K partial)
template<int BM, int BN, int MODE>
__global__ __launch_bounds__(256, 2) void k_gemm(
    const u16* __restrict__ A, const u16* __restrict__ Bt,
    int M, int N, int K, int ksplit,
    u16* __restrict__ obf, float* __restrict__ of32,
    const float* __restrict__ e1, const float* __restrict__ e2) {
  constexpr int BK = 32;
  constexpr int WC = (BN == 128) ? 2 : 1;
  constexpr int WR = 4 / WC;
  constexpr int WM = BM / WR;   // 128 or 32
  constexpr int WN = BN / WC;   // 64
  constexpr int MFR = WM / 16;  // 8 or 2
  constexpr int NFR = WN / 16;  // 4
  constexpr int AISS = BM / 64; // gload issues per stage
  constexpr int BISS = BN / 64;
  constexpr int ISS = AISS + BISS;
  __shared__ u16 As[3][BM * BK];
  __shared__ u16 Bs[3][BN * BK];
  int tid = threadIdx.x, lane = tid & 63, wid = tid >> 6;
  int wr = wid / WC, wc = wid % WC;
  int fr = lane & 15, fg = lane >> 4, fk = fg * 8;

  // T1 bijective XCD swizzle (all grids: nwg % 8 == 0)
  int gx = gridDim.x;
  int nwg = gx * gridDim.y;
  int orig = blockIdx.y * gx + blockIdx.x;
  int swz = (orig & 7) * (nwg >> 3) + (orig >> 3);
  int bx = swz % gx, by = swz / gx;
  int m0 = by * BM, n0 = bx * BN;
  int Kc = K / ksplit, k0 = blockIdx.z * Kc;

  f32x4 acc[MFR][NFR] = {};

  // staging: thread -> (row r in 64-row issue group, swizzled 8-elem chunk)
  int r = tid >> 2;
  int cswz = ((tid & 3) * 8) ^ (((r >> 1) & 3) << 3);
  const u16* Ag = A + (size_t)(m0 + r) * K + k0 + cswz;
  const u16* Bg = Bt + (size_t)(n0 + r) * K + k0 + cswz;

#define STAGE(t2, b_) do {                                               \
    int kt_ = (t2) * BK;                                                 \
    _Pragma("unroll")                                                    \
    for (int i_ = 0; i_ < AISS; i_++)                                    \
      gload16(Ag + kt_ + (size_t)(i_ * 64) * K, &As[b_][i_ * 2048 + wid * 512]); \
    _Pragma("unroll")                                                    \
    for (int i_ = 0; i_ < BISS; i_++)                                    \
      gload16(Bg + kt_ + (size_t)(i_ * 64) * K, &Bs[b_][i_ * 2048 + wid * 512]); \
  } while (0)

  // lane-constant swizzled k-column for fragment reads
  int ce = fk ^ (((fr >> 1) & 3) << 3);

  int nt = Kc / BK;
  STAGE(0, 0);
  STAGE(1, 1);

  int cur = 0, sb = 2;   // read buffer t%3 ; stage buffer (t+2)%3
  for (int t = 0; t < nt; t++) {
    // bar: my stage(t) landed (vmcnt) + everyone's landed (barrier)
    if (t == nt - 1) {
      asm volatile("s_waitcnt vmcnt(0)\n\ts_barrier" ::: "memory");
    } else if constexpr (ISS == 6) {
      asm volatile("s_waitcnt vmcnt(6)\n\ts_barrier" ::: "memory");
    } else if constexpr (ISS == 4) {
      asm volatile("s_waitcnt vmcnt(4)\n\ts_barrier" ::: "memory");
    } else {
      asm volatile("s_waitcnt vmcnt(3)\n\ts_barrier" ::: "memory");
    }

    if (t + 2 < nt) STAGE(t + 2, sb);   // issue early; lands by bar(t+2)

    bf16x8 af[MFR], bv[NFR];
#pragma unroll
    for (int mi = 0; mi < MFR; mi++)
      af[mi] = *reinterpret_cast<const bf16x8*>(&As[cur][(wr * WM + mi * 16 + fr) * BK + ce]);
#pragma unroll
    for (int ni = 0; ni < NFR; ni++)
      bv[ni] = *reinterpret_cast<const bf16x8*>(&Bs[cur][(wc * WN + ni * 16 + fr) * BK + ce]);

    __builtin_amdgcn_s_setprio(1);
#pragma unroll
    for (int mi = 0; mi < MFR; mi++)
#pragma unroll
      for (int ni = 0; ni < NFR; ni++)
        acc[mi][ni] = __builtin_amdgcn_mfma_f32_16x16x32_bf16(af[mi], bv[ni], acc[mi][ni], 0, 0, 0);
    __builtin_amdgcn_s_setprio(0);

    cur = (cur == 2) ? 0 : cur + 1;
    sb = (sb == 2) ? 0 : sb + 1;
  }
#undef STAGE

  float* part = (MODE == 3) ? of32 + (size_t)blockIdx.z * ((size_t)M * N) : of32;
#pragma unroll
  for (int mi = 0; mi < MFR; mi++) {
#pragma unroll
    for (int ni = 0; ni < NFR; ni++) {
#pragma unroll
      for (int i = 0; i < 4; i++) {
        int row = m0 + wr * WM + mi * 16 + fg * 4 + i;
        int col = n0 + wc * WN + ni * 16 + fr;
        float v = acc[mi][ni][i];
        size_t idx = (size_t)row * N + col;
        if constexpr (MODE == 0) {
          obf[idx] = f2bf(v);
        } else if constexpr (MODE == 1) {
          float t = e1[idx] + 0.2f * v + e2[col];
          of32[idx] = t;
          obf[idx] = f2bf(t);
        } else if constexpr (MODE == 2) {
          float t = v + e1[col];
          obf[idx] = f2bf(t > 0.f ? t : 0.f);
        } else {
          part[idx] = v;
        }
      }
    }
  }
}

// ---------------- ffn2 split-K reduce + residual + biases ----------------
// out = p0+p1+p2+p3 + x1f + b2[col] + nb2[col]
__global__ void k_ffn2_reduce(const float* __restrict__ p, const float* __restrict__ x1f,
                              const float* __restrict__ b2, const float* __restrict__ nb2,
                              float* __restrict__ out) {
  int i = blockIdx.x * 256 + threadIdx.x;
  int col4 = (i * 4) % HDIM;
  float4 s = reinterpret_cast<const float4*>(x1f)[i];
  float4 bb = *reinterpret_cast<const float4*>(b2 + col4);
  float4 nn = *reinterpret_cast<const float4*>(nb2 + col4);
  s.x += bb.x + nn.x; s.y += bb.y + nn.y; s.z += bb.z + nn.z; s.w += bb.w + nn.w;
#pragma unroll
  for (int z = 0; z < 4; z++) {
    float4 pv = reinterpret_cast<const float4*>(p + (size_t)z * ROWS * HDIM)[i];
    s.x += pv.x; s.y += pv.y; s.z += pv.z; s.w += pv.w;
  }
  reinterpret_cast<float4*>(out)[i] = s;
}

// ---------------- fused 2quad attention (8 waves, 128 q-rows/block) ----------------
// 1D grid, bid = t0i*48 + bh: all 8 t0-blocks of one (b,h) share bid%8 -> same
// XCD -> K/V L2-resident (6 pairs x 256KB per XCD).
__global__ __launch_bounds__(512) void k_attn(
    const u16* __restrict__ qkv, const float* __restrict__ mask,
    const float* __restrict__ tau, u16* __restrict__ outp) {
  __shared__ u16 Ks[64 * 72];
  __shared__ u16 Vs[64 * 64];
  __shared__ u16 Ps[8 * 1024];
  int tid = threadIdx.x, lane = tid & 63, w = tid >> 6;
  int bid = blockIdx.x;
  int bh = bid % 48, t0i = bid / 48;
  int h = bh >> 2, b = bh & 3;
  int fr = lane & 15, fg = lane >> 4, fk = fg * 8;
  int rb = b * SEQ;
  float rs = 1.0f / (8.0f * tau[h]);
  float rs2 = rs * rs;

  int t0 = t0i * 128 + w * 16;
  const u16* qrow = qkv + (size_t)(rb + t0 + fr) * QKV3 + h * 64;
  bf16x8 aq0 = *reinterpret_cast<const bf16x8*>(qrow + fk);
  bf16x8 aq1 = *reinterpret_cast<const bf16x8*>(qrow + 32 + fk);

  f32x4 acco[4] = {};
  f32x4 accd = {};

  int sr = tid >> 3, c = tid & 7;
  const u16* kg = qkv + (size_t)(rb + sr) * QKV3 + HDIM + h * 64 + c * 8;
  const u16* vg = kg + HDIM;
  u16* kw = &Ks[sr * 72 + c * 8];
  u16* vw = &Vs[((sr >> 2) * 4 + (c >> 1)) * 64 + (sr & 3) * 16 + (c & 1) * 8];
  unsigned psb = ldsoff(&Ps[w * 1024]);
  unsigned vsb = ldsoff(Vs);

  __bf16 onev = (__bf16)1.0f;
  bf16x8 ones = {onev, onev, onev, onev, onev, onev, onev, onev};

  int4 kreg = *reinterpret_cast<const int4*>(kg);
  int4 vreg = *reinterpret_cast<const int4*>(vg);

  for (int st = 0; st < SEQ; st += 64) {
    __syncthreads();
    *reinterpret_cast<int4*>(kw) = kreg;
    *reinterpret_cast<int4*>(vw) = vreg;
    __syncthreads();
    if (st + 64 < SEQ) {
      kreg = *reinterpret_cast<const int4*>(kg + (size_t)(st + 64) * QKV3);
      vreg = *reinterpret_cast<const int4*>(vg + (size_t)(st + 64) * QKV3);
    }

#pragma unroll
    for (int sf = 0; sf < 4; sf++) {
      bf16x8 bk0 = *reinterpret_cast<const bf16x8*>(&Ks[(sf * 16 + fr) * 72 + fk]);
      bf16x8 bk1 = *reinterpret_cast<const bf16x8*>(&Ks[(sf * 16 + fr) * 72 + 32 + fk]);
      f32x4 s = {};
      s = __builtin_amdgcn_mfma_f32_16x16x32_bf16(aq0, bk0, s, 0, 0, 0);
      s = __builtin_amdgcn_mfma_f32_16x16x32_bf16(aq1, bk1, s, 0, 0, 0);
      float rm = rs2 * mask[b * SEQ + st + sf * 16 + fr];
      u64 pw = 0;
#pragma unroll
      for (int i = 0; i < 4; i++) {
        float wv = s[i] * s[i] * rm;
        pw |= (u64)f2bf(wv) << (16 * i);
      }
      *reinterpret_cast<u64*>(&Ps[w * 1024 + (sf * 4 + (fr >> 2)) * 64 + (fr & 3) * 16 + fg * 4]) = pw;
    }
    asm volatile("s_waitcnt lgkmcnt(0)" ::: "memory");
    __builtin_amdgcn_sched_barrier(0);

    u64 pa0 = tr8(psb + (fg * 2 + 0) * 128 + fr * 2);
    u64 pa1 = tr8(psb + (fg * 2 + 1) * 128 + fr * 2);
    u64 pa2 = tr8(psb + (8 + fg * 2 + 0) * 128 + fr * 2);
    u64 pa3 = tr8(psb + (8 + fg * 2 + 1) * 128 + fr * 2);
    u64 vb[4][4];
#pragma unroll
    for (int df = 0; df < 4; df++) {
      vb[df][0] = tr8(vsb + ((fg * 2 + 0) * 4 + df) * 128 + fr * 2);
      vb[df][1] = tr8(vsb + ((fg * 2 + 1) * 4 + df) * 128 + fr * 2);
      vb[df][2] = tr8(vsb + ((8 + fg * 2 + 0) * 4 + df) * 128 + fr * 2);
      vb[df][3] = tr8(vsb + ((8 + fg * 2 + 1) * 4 + df) * 128 + fr * 2);
    }
    asm volatile("s_waitcnt lgkmcnt(0)" ::: "memory");
    __builtin_amdgcn_sched_barrier(0);

    B8 ap0, ap1;
    ap0.q[0] = pa0; ap0.q[1] = pa1;
    ap1.q[0] = pa2; ap1.q[1] = pa3;
#pragma unroll
    for (int df = 0; df < 4; df++) {
      B8 b0, b1;
      b0.q[0] = vb[df][0]; b0.q[1] = vb[df][1];
      b1.q[0] = vb[df][2]; b1.q[1] = vb[df][3];
      acco[df] = __builtin_amdgcn_mfma_f32_16x16x32_bf16(ap0.v, b0.v, acco[df], 0, 0, 0);
      acco[df] = __builtin_amdgcn_mfma_f32_16x16x32_bf16(ap1.v, b1.v, acco[df], 0, 0, 0);
    }
    accd = __builtin_amdgcn_mfma_f32_16x16x32_bf16(ap0.v, ones, accd, 0, 0, 0);
    accd = __builtin_amdgcn_mfma_f32_16x16x32_bf16(ap1.v, ones, accd, 0, 0, 0);
  }

#pragma unroll
  for (int df = 0; df < 4; df++)
#pragma unroll
    for (int i = 0; i < 4; i++) {
      int t = t0 + fg * 4 + i;
      int col = h * 64 + df * 16 + fr;
      float o = acco[df][i] / (accd[i] + 1e-6f);
      outp[(size_t)(rb + t) * HDIM + col] = f2bf(o);
    }
}

extern "C" void kernel_launch(void* const* d_in, const int* in_sizes, int n_in,
                              void* d_out, int out_size, void* d_ws, size_t ws_size,
                              hipStream_t stream) {
  const float* x     = (const float*)d_in[0];
  const float* mask  = (const float*)d_in[1];
  const float* w_qkv = (const float*)d_in[2];
  const float* w_o   = (const float*)d_in[3];
  const float* tau   = (const float*)d_in[4];
  const float* w1    = (const float*)d_in[5];
  const float* b1    = (const float*)d_in[6];
  const float* w2    = (const float*)d_in[7];
  const float* b2    = (const float*)d_in[8];
  const float* nb1   = (const float*)d_in[9];
  const float* nb2   = (const float*)d_in[10];
  float* out = (float*)d_out;
  (void)ws_size; (void)in_sizes; (void)n_in; (void)out_size;

  char* base = (char*)d_ws;
  float* part = (float*)base;                 // [4][ROWS][HDIM] f32 (48 MiB), live only in ffn2
  u16* xb    = (u16*)(base);
  u16* wqkvT = (u16*)(base + 6291456);
  u16* woT   = (u16*)(base + 9830400);
  u16* w1T   = (u16*)(base + 11010048);
  u16* qkvb  = (u16*)(base + 15728640);
  u16* attnb = (u16*)(base + 34603008);
  u16* x1b   = (u16*)(base + 40894464);
  u16* w2T   = (u16*)(base + 50331648);
  float* x1f = (float*)(base + 55050240);
  u16* hb    = (u16*)(base + 67633152);

  k_prep<<<9984, 256, 0, stream>>>(x, xb, w_qkv, wqkvT, w_o, woT, w1, w1T, w2, w2T);

  // qkv = x @ w_qkv -> bf16   (grid 18x16 = 288)
  k_gemm<256, 128, 0><<<dim3(QKV3 / 128, ROWS / 256), 256, 0, stream>>>(
      xb, wqkvT, ROWS, QKV3, HDIM, 1, qkvb, nullptr, nullptr, nullptr);
  // attention (1D bh-chunked grid: 8 * 48 = 384)
  k_attn<<<384, 512, 0, stream>>>(qkvb, mask, tau, attnb);
  // x1 = x + 0.2*(attn @ w_o) + nb1   (grid 12x32 = 384)
  k_gemm<128, 64, 1><<<dim3(HDIM / 64, ROWS / 128), 256, 0, stream>>>(
      attnb, woT, ROWS, HDIM, HDIM, 1, x1b, x1f, x, nb1);
  // h = relu(x1 @ w1 + b1)   (grid 24x16 = 384)
  k_gemm<256, 128, 2><<<dim3(INTERDIM / 128, ROWS / 256), 256, 0, stream>>>(
      x1b, w1T, ROWS, INTERDIM, HDIM, 1, hb, nullptr, b1, nullptr);
  // ffn2 split-K=4 partials   (grid 6x16x4 = 384)
  k_gemm<256, 128, 3><<<dim3(HDIM / 128, ROWS / 256, 4), 256, 0, stream>>>(
      hb, w2T, ROWS, HDIM, INTERDIM, 4, nullptr, part, nullptr, nullptr);
  // out = sum(partials) + x1f + b2 + nb2
  k_ffn2_reduce<<<ROWS * HDIM / 4 / 256, 256, 0, stream>>>(part, x1f, b2, nb2, out);
}

// Round 12
// 146.928 us; speedup vs baseline: 1.1567x; 1.1567x over previous
//
#include <hip/hip_runtime.h>

typedef __bf16 bf16x8 __attribute__((ext_vector_type(8)));
typedef float f32x4 __attribute__((ext_vector_type(4)));
typedef unsigned short u16;
typedef unsigned long long u64;

#define HDIM 768
#define NHEADS 12
#define SEQ 1024
#define NBATCH 4
#define ROWS 4096      // B*T
#define QKV3 2304
#define INTERDIM 3072

__device__ __forceinline__ u16 f2bf(float f) {
  union { float f; unsigned int u; } v; v.f = f;
  unsigned int r = v.u + 0x7fffu + ((v.u >> 16) & 1u);
  return (u16)(r >> 16);
}

__device__ __forceinline__ float bf2f(u16 b) {
  union { unsigned int u; float f; } v; v.u = (unsigned int)b << 16;
  return v.f;
}

// async global->LDS, 16B per lane. LDS dest is wave-uniform base + lane*16.
__device__ __forceinline__ void gload16(const u16* g, u16* l) {
  __builtin_amdgcn_global_load_lds(
      (const __attribute__((address_space(1))) void*)g,
      (__attribute__((address_space(3))) void*)l, 16, 0, 0);
}

__device__ __forceinline__ unsigned ldsoff(const void* p) {
  return (unsigned)(unsigned long long)(const __attribute__((address_space(3))) char*)p;
}

// hardware transpose read: lane gets 4 bf16 at [a, a+32B, a+64B, a+96B]
__device__ __forceinline__ u64 tr8(unsigned a) {
  u64 r;
  asm volatile("ds_read_b64_tr_b16 %0, %1" : "=v"(r) : "v"(a));
  return r;
}

union B8 { u64 q[2]; bf16x8 v; };

// ---------------- fused pre-pass: x->bf16 + 4 weight transposes ----------------
__global__ __launch_bounds__(256) void k_prep(
    const float* __restrict__ x, u16* __restrict__ xb,
    const float* __restrict__ wqkv, u16* __restrict__ wqkvT,
    const float* __restrict__ wo, u16* __restrict__ woT,
    const float* __restrict__ w1, u16* __restrict__ w1T,
    const float* __restrict__ w2, u16* __restrict__ w2T) {
  __shared__ float tile[32][33];
  int bid = blockIdx.x, tid = threadIdx.x;
  if (bid < 3072) {
    int i = bid * 256 + tid;
    float4 f = reinterpret_cast<const float4*>(x)[i];
    ushort4 o;
    o.x = f2bf(f.x); o.y = f2bf(f.y); o.z = f2bf(f.z); o.w = f2bf(f.w);
    reinterpret_cast<ushort4*>(xb)[i] = o;
    return;
  }
  const float* in; u16* outp; int K, N, t;
  if (bid < 4800)      { in = wqkv; outp = wqkvT; K = 768;  N = 2304; t = bid - 3072; }
  else if (bid < 5376) { in = wo;   outp = woT;   K = 768;  N = 768;  t = bid - 4800; }
  else if (bid < 7680) { in = w1;   outp = w1T;   K = 768;  N = 3072; t = bid - 5376; }
  else                 { in = w2;   outp = w2T;   K = 3072; N = 768;  t = bid - 7680; }
  int ntx = N >> 5;
  int bx = t % ntx, by = t / ntx;
  int tx = tid & 31, ty = tid >> 5;
  int n0 = bx * 32, k0 = by * 32;
#pragma unroll
  for (int i = 0; i < 32; i += 8)
    tile[ty + i][tx] = in[(size_t)(k0 + ty + i) * N + n0 + tx];
  __syncthreads();
#pragma unroll
  for (int i = 0; i < 32; i += 8)
    outp[(size_t)(n0 + ty + i) * K + k0 + tx] = f2bf(tile[tx][ty + i]);
}

// ============ MFMA GEMM, BK=32, dbuf LDS, counted vmcnt (round-10 struct) ============
// C = A[M][K] * Bt[N][K]^T. Prologue stages tiles 0,1; tile t:
//   vmcnt(ISS)+barrier; ds_read frags; lgkmcnt(0)+barrier; stage(t+2); MFMA.
// Swizzle (both sides): 8-elem chunk ^= (row>>1)&3  (verified: 0 conflicts).
// BM=256,BN=128: waves 2x2, wave 128x64.  BM=128,BN=64: waves 4x1, wave 32x64.
// modes: 0: obf=bf16(C)                                   (qkv)
//        1: obf=bf16(e1[idx]+0.2*C+e2[col])               (w_o + residual, bf16 only)
//        2: obf=bf16(relu(C+e1[col]))                     (ffn1)
//        3: obf[z*M*N+idx]=bf16(C)                        (ffn2 split-K partial, bf16)
template<int BM, int BN, int MODE>
__global__ __launch_bounds__(256, 2) void k_gemm(
    const u16* __restrict__ A, const u16* __restrict__ Bt,
    int M, int N, int K, int ksplit,
    u16* __restrict__ obf,
    const float* __restrict__ e1, const float* __restrict__ e2) {
  constexpr int BK = 32;
  constexpr int WC = (BN == 128) ? 2 : 1;
  constexpr int WR = 4 / WC;
  constexpr int WM = BM / WR;   // 128 or 32
  constexpr int WN = BN / WC;   // 64
  constexpr int MFR = WM / 16;  // 8 or 2
  constexpr int NFR = WN / 16;  // 4
  constexpr int AISS = BM / 64; // gload issues per stage
  constexpr int BISS = BN / 64;
  constexpr int ISS = AISS + BISS;
  __shared__ u16 As[2][BM * BK];
  __shared__ u16 Bs[2][BN * BK];
  int tid = threadIdx.x, lane = tid & 63, wid = tid >> 6;
  int wr = wid / WC, wc = wid % WC;
  int fr = lane & 15, fg = lane >> 4, fk = fg * 8;

  // T1 bijective XCD swizzle (all grids: nwg % 8 == 0)
  int gx = gridDim.x;
  int nwg = gx * gridDim.y;
  int orig = blockIdx.y * gx + blockIdx.x;
  int swz = (orig & 7) * (nwg >> 3) + (orig >> 3);
  int bx = swz % gx, by = swz / gx;
  int m0 = by * BM, n0 = bx * BN;
  int Kc = K / ksplit, k0 = blockIdx.z * Kc;

  f32x4 acc[MFR][NFR] = {};

  // staging: thread -> (row r in 64-row issue group, swizzled 8-elem chunk)
  int r = tid >> 2;
  int cswz = ((tid & 3) * 8) ^ (((r >> 1) & 3) << 3);
  const u16* Ag = A + (size_t)(m0 + r) * K + k0 + cswz;
  const u16* Bg = Bt + (size_t)(n0 + r) * K + k0 + cswz;

#define STAGE(t2) do {                                                   \
    int b_ = (t2) & 1; int kt_ = (t2) * BK;                              \
    _Pragma("unroll")                                                    \
    for (int i_ = 0; i_ < AISS; i_++)                                    \
      gload16(Ag + kt_ + (size_t)(i_ * 64) * K, &As[b_][i_ * 2048 + wid * 512]); \
    _Pragma("unroll")                                                    \
    for (int i_ = 0; i_ < BISS; i_++)                                    \
      gload16(Bg + kt_ + (size_t)(i_ * 64) * K, &Bs[b_][i_ * 2048 + wid * 512]); \
  } while (0)

  // lane-constant swizzled k-column for fragment reads
  int ce = fk ^ (((fr >> 1) & 3) << 3);

  int nt = Kc / BK;
  STAGE(0);
  STAGE(1);

  for (int t = 0; t < nt; t++) {
    int cur = t & 1;
    // bar1: my stage(t) landed (vmcnt) + everyone's landed (barrier)
    if (t == nt - 1) {
      asm volatile("s_waitcnt vmcnt(0)\n\ts_barrier" ::: "memory");
    } else if constexpr (ISS == 6) {
      asm volatile("s_waitcnt vmcnt(6)\n\ts_barrier" ::: "memory");
    } else if constexpr (ISS == 5) {
      asm volatile("s_waitcnt vmcnt(5)\n\ts_barrier" ::: "memory");
    } else if constexpr (ISS == 4) {
      asm volatile("s_waitcnt vmcnt(4)\n\ts_barrier" ::: "memory");
    } else {
      asm volatile("s_waitcnt vmcnt(3)\n\ts_barrier" ::: "memory");
    }

    bf16x8 af[MFR], bv[NFR];
#pragma unroll
    for (int mi = 0; mi < MFR; mi++)
      af[mi] = *reinterpret_cast<const bf16x8*>(&As[cur][(wr * WM + mi * 16 + fr) * BK + ce]);
#pragma unroll
    for (int ni = 0; ni < NFR; ni++)
      bv[ni] = *reinterpret_cast<const bf16x8*>(&Bs[cur][(wc * WN + ni * 16 + fr) * BK + ce]);

    // bar2: all waves' reads of buf[cur] retired -> safe to restage it
    asm volatile("s_waitcnt lgkmcnt(0)\n\ts_barrier" ::: "memory");
    if (t + 2 < nt) STAGE(t + 2);

    __builtin_amdgcn_s_setprio(1);
#pragma unroll
    for (int mi = 0; mi < MFR; mi++)
#pragma unroll
      for (int ni = 0; ni < NFR; ni++)
        acc[mi][ni] = __builtin_amdgcn_mfma_f32_16x16x32_bf16(af[mi], bv[ni], acc[mi][ni], 0, 0, 0);
    __builtin_amdgcn_s_setprio(0);
  }
#undef STAGE

  u16* outp = (MODE == 3) ? obf + (size_t)blockIdx.z * ((size_t)M * N) : obf;
#pragma unroll
  for (int mi = 0; mi < MFR; mi++) {
#pragma unroll
    for (int ni = 0; ni < NFR; ni++) {
#pragma unroll
      for (int i = 0; i < 4; i++) {
        int row = m0 + wr * WM + mi * 16 + fg * 4 + i;
        int col = n0 + wc * WN + ni * 16 + fr;
        float v = acc[mi][ni][i];
        size_t idx = (size_t)row * N + col;
        if constexpr (MODE == 0) {
          outp[idx] = f2bf(v);
        } else if constexpr (MODE == 1) {
          outp[idx] = f2bf(e1[idx] + 0.2f * v + e2[col]);
        } else if constexpr (MODE == 2) {
          float t = v + e1[col];
          outp[idx] = f2bf(t > 0.f ? t : 0.f);
        } else {
          outp[idx] = f2bf(v);
        }
      }
    }
  }
}

// ---------------- ffn2 split-K reduce + residual + biases (bf16 inputs) ----------------
// out = sum_z bf2f(p[z]) + bf2f(x1b) + b2[col] + nb2[col]   (f32 out)
__global__ void k_ffn2_reduce(const u16* __restrict__ p, const u16* __restrict__ x1b,
                              const float* __restrict__ b2, const float* __restrict__ nb2,
                              float* __restrict__ out) {
  int i = blockIdx.x * 256 + threadIdx.x;   // 4-elem index
  int col4 = (i * 4) % HDIM;
  ushort4 xv = reinterpret_cast<const ushort4*>(x1b)[i];
  float4 bb = *reinterpret_cast<const float4*>(b2 + col4);
  float4 nn = *reinterpret_cast<const float4*>(nb2 + col4);
  float4 s;
  s.x = bf2f(xv.x) + bb.x + nn.x;
  s.y = bf2f(xv.y) + bb.y + nn.y;
  s.z = bf2f(xv.z) + bb.z + nn.z;
  s.w = bf2f(xv.w) + bb.w + nn.w;
#pragma unroll
  for (int z = 0; z < 4; z++) {
    ushort4 pv = reinterpret_cast<const ushort4*>(p + (size_t)z * ROWS * HDIM)[i];
    s.x += bf2f(pv.x); s.y += bf2f(pv.y); s.z += bf2f(pv.z); s.w += bf2f(pv.w);
  }
  reinterpret_cast<float4*>(out)[i] = s;
}

// ---------------- fused 2quad attention (8 waves, 128 q-rows/block) ----------------
// 1D grid, bid = t0i*48 + bh: all 8 t0-blocks of one (b,h) share bid%8 -> same
// XCD -> K/V L2-resident (6 pairs x 256KB per XCD).
__global__ __launch_bounds__(512) void k_attn(
    const u16* __restrict__ qkv, const float* __restrict__ mask,
    const float* __restrict__ tau, u16* __restrict__ outp) {
  __shared__ u16 Ks[64 * 72];
  __shared__ u16 Vs[64 * 64];
  __shared__ u16 Ps[8 * 1024];
  int tid = threadIdx.x, lane = tid & 63, w = tid >> 6;
  int bid = blockIdx.x;
  int bh = bid % 48, t0i = bid / 48;
  int h = bh >> 2, b = bh & 3;
  int fr = lane & 15, fg = lane >> 4, fk = fg * 8;
  int rb = b * SEQ;
  float rs = 1.0f / (8.0f * tau[h]);
  float rs2 = rs * rs;

  int t0 = t0i * 128 + w * 16;
  const u16* qrow = qkv + (size_t)(rb + t0 + fr) * QKV3 + h * 64;
  bf16x8 aq0 = *reinterpret_cast<const bf16x8*>(qrow + fk);
  bf16x8 aq1 = *reinterpret_cast<const bf16x8*>(qrow + 32 + fk);

  f32x4 acco[4] = {};
  f32x4 accd = {};

  int sr = tid >> 3, c = tid & 7;
  const u16* kg = qkv + (size_t)(rb + sr) * QKV3 + HDIM + h * 64 + c * 8;
  const u16* vg = kg + HDIM;
  u16* kw = &Ks[sr * 72 + c * 8];
  u16* vw = &Vs[((sr >> 2) * 4 + (c >> 1)) * 64 + (sr & 3) * 16 + (c & 1) * 8];
  unsigned psb = ldsoff(&Ps[w * 1024]);
  unsigned vsb = ldsoff(Vs);

  __bf16 onev = (__bf16)1.0f;
  bf16x8 ones = {onev, onev, onev, onev, onev, onev, onev, onev};

  int4 kreg = *reinterpret_cast<const int4*>(kg);
  int4 vreg = *reinterpret_cast<const int4*>(vg);

  for (int st = 0; st < SEQ; st += 64) {
    __syncthreads();
    *reinterpret_cast<int4*>(kw) = kreg;
    *reinterpret_cast<int4*>(vw) = vreg;
    __syncthreads();
    if (st + 64 < SEQ) {
      kreg = *reinterpret_cast<const int4*>(kg + (size_t)(st + 64) * QKV3);
      vreg = *reinterpret_cast<const int4*>(vg + (size_t)(st + 64) * QKV3);
    }

#pragma unroll
    for (int sf = 0; sf < 4; sf++) {
      bf16x8 bk0 = *reinterpret_cast<const bf16x8*>(&Ks[(sf * 16 + fr) * 72 + fk]);
      bf16x8 bk1 = *reinterpret_cast<const bf16x8*>(&Ks[(sf * 16 + fr) * 72 + 32 + fk]);
      f32x4 s = {};
      s = __builtin_amdgcn_mfma_f32_16x16x32_bf16(aq0, bk0, s, 0, 0, 0);
      s = __builtin_amdgcn_mfma_f32_16x16x32_bf16(aq1, bk1, s, 0, 0, 0);
      float rm = rs2 * mask[b * SEQ + st + sf * 16 + fr];
      u64 pw = 0;
#pragma unroll
      for (int i = 0; i < 4; i++) {
        float wv = s[i] * s[i] * rm;
        pw |= (u64)f2bf(wv) << (16 * i);
      }
      *reinterpret_cast<u64*>(&Ps[w * 1024 + (sf * 4 + (fr >> 2)) * 64 + (fr & 3) * 16 + fg * 4]) = pw;
    }
    asm volatile("s_waitcnt lgkmcnt(0)" ::: "memory");
    __builtin_amdgcn_sched_barrier(0);

    u64 pa0 = tr8(psb + (fg * 2 + 0) * 128 + fr * 2);
    u64 pa1 = tr8(psb + (fg * 2 + 1) * 128 + fr * 2);
    u64 pa2 = tr8(psb + (8 + fg * 2 + 0) * 128 + fr * 2);
    u64 pa3 = tr8(psb + (8 + fg * 2 + 1) * 128 + fr * 2);
    u64 vb[4][4];
#pragma unroll
    for (int df = 0; df < 4; df++) {
      vb[df][0] = tr8(vsb + ((fg * 2 + 0) * 4 + df) * 128 + fr * 2);
      vb[df][1] = tr8(vsb + ((fg * 2 + 1) * 4 + df) * 128 + fr * 2);
      vb[df][2] = tr8(vsb + ((8 + fg * 2 + 0) * 4 + df) * 128 + fr * 2);
      vb[df][3] = tr8(vsb + ((8 + fg * 2 + 1) * 4 + df) * 128 + fr * 2);
    }
    asm volatile("s_waitcnt lgkmcnt(0)" ::: "memory");
    __builtin_amdgcn_sched_barrier(0);

    B8 ap0, ap1;
    ap0.q[0] = pa0; ap0.q[1] = pa1;
    ap1.q[0] = pa2; ap1.q[1] = pa3;
#pragma unroll
    for (int df = 0; df < 4; df++) {
      B8 b0, b1;
      b0.q[0] = vb[df][0]; b0.q[1] = vb[df][1];
      b1.q[0] = vb[df][2]; b1.q[1] = vb[df][3];
      acco[df] = __builtin_amdgcn_mfma_f32_16x16x32_bf16(ap0.v, b0.v, acco[df], 0, 0, 0);
      acco[df] = __builtin_amdgcn_mfma_f32_16x16x32_bf16(ap1.v, b1.v, acco[df], 0, 0, 0);
    }
    accd = __builtin_amdgcn_mfma_f32_16x16x32_bf16(ap0.v, ones, accd, 0, 0, 0);
    accd = __builtin_amdgcn_mfma_f32_16x16x32_bf16(ap1.v, ones, accd, 0, 0, 0);
  }

#pragma unroll
  for (int df = 0; df < 4; df++)
#pragma unroll
    for (int i = 0; i < 4; i++) {
      int t = t0 + fg * 4 + i;
      int col = h * 64 + df * 16 + fr;
      float o = acco[df][i] / (accd[i] + 1e-6f);
      outp[(size_t)(rb + t) * HDIM + col] = f2bf(o);
    }
}

extern "C" void kernel_launch(void* const* d_in, const int* in_sizes, int n_in,
                              void* d_out, int out_size, void* d_ws, size_t ws_size,
                              hipStream_t stream) {
  const float* x     = (const float*)d_in[0];
  const float* mask  = (const float*)d_in[1];
  const float* w_qkv = (const float*)d_in[2];
  const float* w_o   = (const float*)d_in[3];
  const float* tau   = (const float*)d_in[4];
  const float* w1    = (const float*)d_in[5];
  const float* b1    = (const float*)d_in[6];
  const float* w2    = (const float*)d_in[7];
  const float* b2    = (const float*)d_in[8];
  const float* nb1   = (const float*)d_in[9];
  const float* nb2   = (const float*)d_in[10];
  float* out = (float*)d_out;
  (void)ws_size; (void)in_sizes; (void)n_in; (void)out_size;

  char* base = (char*)d_ws;
  u16* partb = (u16*)base;                    // [4][ROWS][HDIM] bf16 (25 MiB), live only in ffn2
  u16* xb    = (u16*)(base);
  u16* wqkvT = (u16*)(base + 6291456);
  u16* woT   = (u16*)(base + 9830400);
  u16* w1T   = (u16*)(base + 11010048);
  u16* qkvb  = (u16*)(base + 15728640);       // dead after attn; partb fits in [0, 25.2MB)
  u16* attnb = (u16*)(base + 34603008);
  u16* x1b   = (u16*)(base + 40894464);       // live through reduce; no overlap with partb
  u16* w2T   = (u16*)(base + 50331648);
  u16* hb    = (u16*)(base + 67633152);

  k_prep<<<9984, 256, 0, stream>>>(x, xb, w_qkv, wqkvT, w_o, woT, w1, w1T, w2, w2T);

  // qkv = x @ w_qkv -> bf16   (grid 18x16 = 288)
  k_gemm<256, 128, 0><<<dim3(QKV3 / 128, ROWS / 256), 256, 0, stream>>>(
      xb, wqkvT, ROWS, QKV3, HDIM, 1, qkvb, nullptr, nullptr);
  // attention (1D bh-chunked grid: 8 * 48 = 384)
  k_attn<<<384, 512, 0, stream>>>(qkvb, mask, tau, attnb);
  // x1 = bf16(x + 0.2*(attn @ w_o) + nb1)   (grid 12x32 = 384)
  k_gemm<128, 64, 1><<<dim3(HDIM / 64, ROWS / 128), 256, 0, stream>>>(
      attnb, woT, ROWS, HDIM, HDIM, 1, x1b, x, nb1);
  // h = relu(x1 @ w1 + b1)   (grid 24x16 = 384)
  k_gemm<256, 128, 2><<<dim3(INTERDIM / 128, ROWS / 256), 256, 0, stream>>>(
      x1b, w1T, ROWS, INTERDIM, HDIM, 1, hb, b1, nullptr);
  // ffn2 split-K=4 bf16 partials   (grid 6x16x4 = 384)
  k_gemm<256, 128, 3><<<dim3(HDIM / 128, ROWS / 256, 4), 256, 0, stream>>>(
      hb, w2T, ROWS, HDIM, INTERDIM, 4, partb, nullptr, nullptr);
  // out = sum(partials) + x1 + b2 + nb2   (f32)
  k_ffn2_reduce<<<ROWS * HDIM / 4 / 256, 256, 0, stream>>>(partb, x1b, b2, nb2, out);
}